// Round 8
// baseline (168.997 us; speedup 1.0000x reference)
//
#include <hip/hip_runtime.h>
#include <hip/hip_bf16.h>

// B=2 H=16 S=2048 D=64, causal. Output = context (B,H,S,D) ++ attention (B,H,S,S), fp32.
// prep: fp32->bf16 pre-swizzled tile images in d_ws (Q/K row-major swz, V transposed swz).
// main: 1024 blocks (1 q-tile each, CU-work-balanced complementary mapping, XCD-pinned
// heads), gl_lds dbuf staging, counted-vmcnt barriers in phase 2, 4 blocks/CU.

constexpr int SEQ = 2048;
constexpr int HD  = 64;
constexpr int NHEADS = 32;   // B*H
constexpr int QT  = 64;
constexpr int NT  = SEQ / QT;

typedef __bf16 bf16x8 __attribute__((ext_vector_type(8)));
typedef unsigned short u16x8 __attribute__((ext_vector_type(8)));
typedef unsigned short u16x4 __attribute__((ext_vector_type(4)));
typedef float f32x4 __attribute__((ext_vector_type(4)));
typedef unsigned short us;

__device__ __forceinline__ us f2bf(float x) {
  unsigned u = __builtin_bit_cast(unsigned, x);
  return (us)((u + 0x7fffu + ((u >> 16) & 1u)) >> 16);  // RNE
}
__device__ __forceinline__ float bf2f(us b) {
  return __builtin_bit_cast(float, (unsigned)b << 16);
}

#define GLOAD_LDS(gp, lp)                                                        \
  __builtin_amdgcn_global_load_lds(                                             \
      (const __attribute__((address_space(1))) void*)(gp),                      \
      (__attribute__((address_space(3))) void*)(lp), 16, 0, 0)

// stage one 8KB tile image -> LDS: 4 waves x 2 calls x 64 lanes x 16B
__device__ __forceinline__ void stage8k(const us* img, us* lds, int w, int l) {
  const char* g = (const char*)img + w * 2048 + l * 16;
  char* s = (char*)lds + w * 2048;
  GLOAD_LDS(g, s);
  GLOAD_LDS(g + 1024, s + 1024);
}

// ============ prep: build bf16 pre-swizzled tile images in scratch ============
// image elem (row r, col c) of Q/K tile at u16-idx (r*64+c) ^ ((r&7)<<3)
// image elem V^T (d, key)            at u16-idx (d*64+key) ^ ((d&7)<<3)
__global__ void prep_kernel(const float* __restrict__ Qg,
                            const float* __restrict__ Kg,
                            const float* __restrict__ Vg,
                            us* __restrict__ ws) {
  const int tile = blockIdx.x & (NT - 1);
  const int bh   = blockIdx.x >> 5;
  const int t = threadIdx.x;
  const size_t tOff = ((size_t)bh * SEQ + (size_t)tile * QT) * HD;
  us* Qi = ws + ((size_t)bh * NT + tile) * 4096;
  us* Ki = Qi + (size_t)NHEADS * NT * 4096;
  us* Vi = Ki + (size_t)NHEADS * NT * 4096;

  #pragma unroll
  for (int g0 = 0; g0 < 2; ++g0) {
    const int g = t + 256 * g0;          // 0..511 image chunks of 8 u16
    const int r = g >> 3, c8 = g & 7;
    const int cp = (8 * c8) ^ ((r & 7) << 3);   // source col for this chunk
    const float* qs = Qg + tOff + (size_t)r * HD + cp;
    const float* ks = Kg + tOff + (size_t)r * HD + cp;
    u16x8 q, k;
    #pragma unroll
    for (int j = 0; j < 8; ++j) { q[j] = f2bf(qs[j]); k[j] = f2bf(ks[j]); }
    *(u16x8*)(Qi + 8 * g) = q;
    *(u16x8*)(Ki + 8 * g) = k;
  }
  #pragma unroll
  for (int g0 = 0; g0 < 2; ++g0) {
    const int g = t + 256 * g0;
    const int d = g >> 3, k8 = g & 7;
    const int kp = (8 * k8) ^ ((d & 7) << 3);   // source key for this chunk
    const float* vs = Vg + tOff + d;
    u16x8 v;
    #pragma unroll
    for (int j = 0; j < 8; ++j) v[j] = f2bf(vs[(size_t)(kp + j) * HD]);
    *(u16x8*)(Vi + 8 * g) = v;
  }
}

// ======================= main attention kernel =======================
__launch_bounds__(256, 4)
__global__ void attn_main(const us* __restrict__ ws, float* __restrict__ out) {
  const int fb = blockIdx.x;                 // 0..1023
  const int g8 = fb >> 8;                    // dispatch "round" 0..3 (CU gets one of each)
  const int r  = fb & 255;
  const int bh = r & (NHEADS - 1);           // fb%8 == bh%8 -> head pinned to one XCD
  const int p  = (r >> 5) | ((g8 & 1) << 3); // 0..15
  const int qt = (g8 >> 1) ? p : (NT - 1 - p); // per-CU {31-p0, 23-p0, p0, p0+8}: sum 62
  const int t  = threadIdx.x;
  const int l  = t & 63;
  const int w  = t >> 6;
  const int l16 = l & 15;
  const int lg  = l >> 4;

  __shared__ __align__(16) us Ks[2][4096];
  __shared__ __align__(16) us Vs[2][4096];     // V^T images
  __shared__ __align__(16) us Ps[4][1024];     // per-wave P strip [q=16][k=64]

  const us* Qi = ws + (size_t)bh * NT * 4096;
  const us* Ki = Qi + (size_t)NHEADS * NT * 4096;
  const us* Vi = Ki + (size_t)NHEADS * NT * 4096;

  float* ctx = out + (size_t)bh * SEQ * HD;
  float* att = out + (size_t)NHEADS * SEQ * HD + (size_t)bh * SEQ * SEQ;

  const float KC = 0.18033688011112042f;  // (1/8) * log2(e)
  const int qbase = qt * QT;
  const int qg = qbase + w * 16 + l16;     // lane's q-row (S^T: col=l16)

  // ---- Q fragments straight from the pre-swizzled image (no LDS) ----
  bf16x8 aq[2];
  {
    const int qr = w * 16 + l16;
    #pragma unroll
    for (int ks = 0; ks < 2; ++ks) {
      const int idx = (qr * 64 + ks * 32 + lg * 8) ^ ((qr & 7) << 3);
      aq[ks] = __builtin_bit_cast(bf16x8, *(const u16x8*)(&Qi[(size_t)qt * 4096 + idx]));
    }
  }

  // issue first K stage, overlap with zero-fill stores, then barrier
  stage8k(Ki, Ks[0], w, l);
  {
    const int zc0 = (qt + 1) * QT;
    const int nz4 = (SEQ - zc0) >> 2;
    for (int rr = 0; rr < QT; ++rr) {
      float* rowp = att + (size_t)(qbase + rr) * SEQ + zc0;
      for (int c = t; c < nz4; c += 256)
        __builtin_nontemporal_store((f32x4){0.f, 0.f, 0.f, 0.f}, (f32x4*)(rowp + 4 * c));
    }
  }
  __syncthreads();

  // ================= phase 1: row sums =================
  float rsum = 0.f;
  {
    int cur = 0;
    for (int kt = 0; kt <= qt; ++kt) {
      if (kt < qt) stage8k(Ki + (size_t)(kt + 1) * 4096, Ks[cur ^ 1], w, l);
      const us* krb = Ks[cur];
      const int kb = kt * QT;
      #pragma unroll
      for (int ct = 0; ct < 4; ++ct) {
        f32x4 acc = {0.f, 0.f, 0.f, 0.f};
        #pragma unroll
        for (int ks = 0; ks < 2; ++ks) {
          const int kr = ct * 16 + l16;
          const int idx = (kr * 64 + ks * 32 + lg * 8) ^ ((kr & 7) << 3);
          bf16x8 bk = __builtin_bit_cast(bf16x8, *(const u16x8*)(&krb[idx]));
          acc = __builtin_amdgcn_mfma_f32_16x16x32_bf16(bk, aq[ks], acc, 0, 0, 0);
        }
        const int kg0 = kb + ct * 16 + lg * 4;
        #pragma unroll
        for (int rr = 0; rr < 4; ++rr) {
          float e = __builtin_amdgcn_exp2f(acc[rr] * KC);
          rsum += (kg0 + rr <= qg) ? e : 0.f;
        }
      }
      __syncthreads();   // drains the 2 staging loads (required anyway)
      cur ^= 1;
    }
  }
  // stage phase-2 tile 0 while reducing
  stage8k(Ki, Ks[0], w, l);
  stage8k(Vi, Vs[0], w, l);
  rsum += __shfl_xor(rsum, 16);
  rsum += __shfl_xor(rsum, 32);
  const float inv = 1.f / rsum;
  __syncthreads();

  // ================= phase 2: P -> att + O = P·V =================
  f32x4 oacc[4];
  #pragma unroll
  for (int ct = 0; ct < 4; ++ct) oacc[ct] = (f32x4){0.f, 0.f, 0.f, 0.f};

  {
    int cur = 0;
    for (int kt = 0; kt <= qt; ++kt) {
      if (kt < qt) {
        stage8k(Ki + (size_t)(kt + 1) * 4096, Ks[cur ^ 1], w, l);
        stage8k(Vi + (size_t)(kt + 1) * 4096, Vs[cur ^ 1], w, l);
      }
      __builtin_amdgcn_sched_barrier(0);   // pin stage ops before compute+stores
      const us* krb = Ks[cur];
      const us* vrb = Vs[cur];
      const int kb = kt * QT;

      // QK^T (swapped) -> normalized bf16 P into own-wave Ps
      #pragma unroll
      for (int ct = 0; ct < 4; ++ct) {
        f32x4 acc = {0.f, 0.f, 0.f, 0.f};
        #pragma unroll
        for (int ks = 0; ks < 2; ++ks) {
          const int kr = ct * 16 + l16;
          const int idx = (kr * 64 + ks * 32 + lg * 8) ^ ((kr & 7) << 3);
          bf16x8 bk = __builtin_bit_cast(bf16x8, *(const u16x8*)(&krb[idx]));
          acc = __builtin_amdgcn_mfma_f32_16x16x32_bf16(bk, aq[ks], acc, 0, 0, 0);
        }
        const int kg0 = kb + ct * 16 + lg * 4;
        u16x4 pb;
        #pragma unroll
        for (int rr = 0; rr < 4; ++rr) {
          float e = __builtin_amdgcn_exp2f(acc[rr] * KC) * inv;
          pb[rr] = f2bf((kg0 + rr <= qg) ? e : 0.f);
        }
        const int pidx = (l16 * 64 + ct * 16 + lg * 4) ^ ((l16 & 7) << 3);
        *(u16x4*)(&Ps[w][pidx]) = pb;
      }

      // att copy: own-wave rows, 256B/row contiguous, nontemporal (4 stores)
      #pragma unroll
      for (int j = 0; j < 4; ++j) {
        const int rloc = lg + 4 * j;
        const int idx = (rloc * 64 + 4 * l16) ^ ((rloc & 7) << 3);
        u16x4 p4 = *(const u16x4*)(&Ps[w][idx]);
        f32x4 pv = { bf2f(p4[0]), bf2f(p4[1]), bf2f(p4[2]), bf2f(p4[3]) };
        __builtin_nontemporal_store(pv,
            (f32x4*)(att + (size_t)(qbase + w * 16 + rloc) * SEQ + kb + 4 * l16));
      }

      // PV (swapped): A = V^T via b128, B = P^T strip (own-wave)
      bf16x8 pa[2];
      #pragma unroll
      for (int ks = 0; ks < 2; ++ks) {
        const int pidx = (l16 * 64 + ks * 32 + lg * 8) ^ ((l16 & 7) << 3);
        pa[ks] = __builtin_bit_cast(bf16x8, *(const u16x8*)(&Ps[w][pidx]));
      }
      #pragma unroll
      for (int ct = 0; ct < 4; ++ct) {
        #pragma unroll
        for (int ks = 0; ks < 2; ++ks) {
          const int dr = ct * 16 + l16;
          const int vidx = (dr * 64 + ks * 32 + lg * 8) ^ ((dr & 7) << 3);
          bf16x8 av = __builtin_bit_cast(bf16x8, *(const u16x8*)(&vrb[vidx]));
          oacc[ct] = __builtin_amdgcn_mfma_f32_16x16x32_bf16(av, pa[ks], oacc[ct], 0, 0, 0);
        }
      }

      // counted barrier: staging (older) must retire; 4 newest att stores may fly
      if (kt < qt) {
        asm volatile("s_waitcnt vmcnt(4) lgkmcnt(0)" ::: "memory");
      } else {
        asm volatile("s_waitcnt lgkmcnt(0)" ::: "memory");
      }
      __builtin_amdgcn_s_barrier();
      __builtin_amdgcn_sched_barrier(0);
      cur ^= 1;
    }
  }

  // ---- context write: lane q=l16 row, d = ct*16+lg*4+r ----
  #pragma unroll
  for (int ct = 0; ct < 4; ++ct)
    __builtin_nontemporal_store(oacc[ct],
        (f32x4*)(ctx + (size_t)qg * HD + ct * 16 + lg * 4));
}

// ======================= fallback (R6, proven 153us) =======================
__launch_bounds__(256, 2)
__global__ void attn_fallback(const float* __restrict__ Qg,
                              const float* __restrict__ Kg,
                              const float* __restrict__ Vg,
                              float* __restrict__ out) {
  const int fb = blockIdx.x;
  const int bh = fb & (NHEADS - 1);
  const int pi = fb >> 5;
  const int t  = threadIdx.x;
  const int l  = t & 63;
  const int w  = t >> 6;
  const int l16 = l & 15;
  const int lg  = l >> 4;

  __shared__ __align__(16) us Qs[QT * HD];
  __shared__ __align__(16) us Ks[QT * HD];
  __shared__ __align__(16) us Vs[QT * HD];
  __shared__ __align__(16) us Ps[4][16 * QT];

  const size_t hoff = (size_t)bh * SEQ * HD;
  const float* Qh = Qg + hoff;
  const float* Kh = Kg + hoff;
  const float* Vh = Vg + hoff;
  float* ctx = out + hoff;
  float* att = out + (size_t)NHEADS * SEQ * HD + (size_t)bh * SEQ * SEQ;

  auto load_tile = [&](const float* src, f32x4 (&reg)[4]) {
    #pragma unroll
    for (int j = 0; j < 4; ++j) {
      const int f = t + 256 * j;
      reg[j] = *(const f32x4*)(src + (size_t)(f >> 4) * HD + 4 * (f & 15));
    }
  };
  auto write_k = [&](const f32x4 (&reg)[4], us* dst) {
    #pragma unroll
    for (int j = 0; j < 4; ++j) {
      const int f = t + 256 * j;
      const int rr = f >> 4, c4 = f & 15;
      const int idx = (rr * 64 + 4 * c4) ^ ((rr & 7) << 3);
      u16x4 b = { f2bf(reg[j].x), f2bf(reg[j].y), f2bf(reg[j].z), f2bf(reg[j].w) };
      *(u16x4*)(&dst[idx]) = b;
    }
  };
  auto write_vv = [&](const f32x4 (&reg)[4], us* dst) {
    #pragma unroll
    for (int j = 0; j < 4; ++j) {
      const int f = t + 256 * j;
      const int rr = f >> 4, c4 = f & 15;
      const int idx = (rr * 64 + 4 * c4) ^ (((rr >> 3) & 3) << 4);
      u16x4 b = { f2bf(reg[j].x), f2bf(reg[j].y), f2bf(reg[j].z), f2bf(reg[j].w) };
      *(u16x4*)(&dst[idx]) = b;
    }
  };

  const float sc = 0.125f;

  for (int half = 0; half < 2; ++half) {
    const int qt = half ? (NT - 1 - pi) : pi;
    const int qbase = qt * QT;
    const int qg = qbase + w * 16 + l16;

    __syncthreads();
    {
      const int zc0 = (qt + 1) * QT;
      const int nz4 = (SEQ - zc0) >> 2;
      for (int rr = 0; rr < QT; ++rr) {
        float* rowp = att + (size_t)(qbase + rr) * SEQ + zc0;
        for (int c = t; c < nz4; c += 256)
          __builtin_nontemporal_store((f32x4){0.f, 0.f, 0.f, 0.f}, (f32x4*)(rowp + 4 * c));
      }
    }
    {
      f32x4 qreg[4];
      load_tile(Qh + (size_t)qbase * HD, qreg);
      write_k(qreg, Qs);
    }
    __syncthreads();

    bf16x8 aq[2];
    #pragma unroll
    for (int ks = 0; ks < 2; ++ks) {
      const int qr = w * 16 + l16;
      const int idx = (qr * 64 + ks * 32 + lg * 8) ^ ((qr & 7) << 3);
      aq[ks] = __builtin_bit_cast(bf16x8, *(const u16x8*)(&Qs[idx]));
    }

    float rsum = 0.f;
    {
      f32x4 kreg[4];
      load_tile(Kh, kreg);
      write_k(kreg, Ks);
      __syncthreads();
      for (int kt = 0; kt <= qt; ++kt) {
        if (kt < qt) load_tile(Kh + (size_t)(kt + 1) * QT * HD, kreg);
        const int kb = kt * QT;
        #pragma unroll
        for (int ct = 0; ct < 4; ++ct) {
          f32x4 acc = {0.f, 0.f, 0.f, 0.f};
          #pragma unroll
          for (int ks = 0; ks < 2; ++ks) {
            const int kr = ct * 16 + l16;
            const int idx = (kr * 64 + ks * 32 + lg * 8) ^ ((kr & 7) << 3);
            bf16x8 bk = __builtin_bit_cast(bf16x8, *(const u16x8*)(&Ks[idx]));
            acc = __builtin_amdgcn_mfma_f32_16x16x32_bf16(bk, aq[ks], acc, 0, 0, 0);
          }
          const int kg0 = kb + ct * 16 + lg * 4;
          #pragma unroll
          for (int rr = 0; rr < 4; ++rr) {
            float e = __expf(acc[rr] * sc);
            rsum += (kg0 + rr <= qg) ? e : 0.f;
          }
        }
        __syncthreads();
        if (kt < qt) write_k(kreg, Ks);
        __syncthreads();
      }
    }
    rsum += __shfl_xor(rsum, 16);
    rsum += __shfl_xor(rsum, 32);
    const float inv = 1.f / rsum;

    f32x4 oacc[4];
    #pragma unroll
    for (int ct = 0; ct < 4; ++ct) oacc[ct] = (f32x4){0.f, 0.f, 0.f, 0.f};

    {
      f32x4 kreg[4], vreg[4];
      load_tile(Kh, kreg);
      load_tile(Vh, vreg);
      write_k(kreg, Ks);
      write_vv(vreg, Vs);
      __syncthreads();
      for (int kt = 0; kt <= qt; ++kt) {
        if (kt < qt) {
          load_tile(Kh + (size_t)(kt + 1) * QT * HD, kreg);
          load_tile(Vh + (size_t)(kt + 1) * QT * HD, vreg);
        }
        const int kb = kt * QT;
        #pragma unroll
        for (int ct = 0; ct < 4; ++ct) {
          f32x4 acc = {0.f, 0.f, 0.f, 0.f};
          #pragma unroll
          for (int ks = 0; ks < 2; ++ks) {
            const int kr = ct * 16 + l16;
            const int idx = (kr * 64 + ks * 32 + lg * 8) ^ ((kr & 7) << 3);
            bf16x8 bk = __builtin_bit_cast(bf16x8, *(const u16x8*)(&Ks[idx]));
            acc = __builtin_amdgcn_mfma_f32_16x16x32_bf16(bk, aq[ks], acc, 0, 0, 0);
          }
          const int kg0 = kb + ct * 16 + lg * 4;
          u16x4 pb;
          #pragma unroll
          for (int rr = 0; rr < 4; ++rr) {
            float e = __expf(acc[rr] * sc) * inv;
            pb[rr] = f2bf((kg0 + rr <= qg) ? e : 0.f);
          }
          const int pidx = (l16 * 64 + ct * 16 + lg * 4) ^ ((l16 & 7) << 3);
          *(u16x4*)(&Ps[w][pidx]) = pb;
        }
        #pragma unroll
        for (int ct = 0; ct < 4; ++ct) {
          #pragma unroll
          for (int ks = 0; ks < 2; ++ks) {
            const int key0 = ks * 32 + lg * 8;
            const int pidx = (l16 * 64 + key0) ^ ((l16 & 7) << 3);
            bf16x8 pa = __builtin_bit_cast(bf16x8, *(const u16x8*)(&Ps[w][pidx]));
            bf16x8 av;
            const int dcol = ct * 16 + l16;
            const int xorv = ((key0 >> 3) & 3) << 4;
            #pragma unroll
            for (int j = 0; j < 8; ++j)
              av[j] = __builtin_bit_cast(__bf16, Vs[((key0 + j) * 64 + dcol) ^ xorv]);
            oacc[ct] = __builtin_amdgcn_mfma_f32_16x16x32_bf16(av, pa, oacc[ct], 0, 0, 0);
          }
        }
        __syncthreads();
        #pragma unroll
        for (int j = 0; j < 4; ++j) {
          const int f = t + 256 * j;
          const int rr = f >> 4, c4 = f & 15;
          const int ww = rr >> 4, qr = rr & 15;
          const int idx = (qr * 64 + 4 * c4) ^ ((qr & 7) << 3);
          u16x4 pb = *(const u16x4*)(&Ps[ww][idx]);
          f32x4 pv = { bf2f(pb[0]), bf2f(pb[1]), bf2f(pb[2]), bf2f(pb[3]) };
          __builtin_nontemporal_store(pv,
              (f32x4*)(att + (size_t)(qbase + rr) * SEQ + kb + 4 * c4));
        }
        if (kt < qt) {
          write_k(kreg, Ks);
          write_vv(vreg, Vs);
        }
        __syncthreads();
      }
    }
    #pragma unroll
    for (int ct = 0; ct < 4; ++ct)
      *(f32x4*)(ctx + (size_t)qg * HD + ct * 16 + lg * 4) = oacc[ct];
  }
}

extern "C" void kernel_launch(void* const* d_in, const int* in_sizes, int n_in,
                              void* d_out, int out_size, void* d_ws, size_t ws_size,
                              hipStream_t stream) {
  const float* Q = (const float*)d_in[0];
  const float* K = (const float*)d_in[1];
  const float* V = (const float*)d_in[2];
  float* out = (float*)d_out;
  const size_t NEED = (size_t)3 * NHEADS * NT * 4096 * sizeof(us);  // 25.2 MB
  if (ws_size >= NEED && d_ws != nullptr) {
    us* wsp = (us*)d_ws;
    prep_kernel<<<dim3(NHEADS * NT), dim3(256), 0, stream>>>(Q, K, V, wsp);
    attn_main<<<dim3(NT * NHEADS), dim3(256), 0, stream>>>(wsp, out);
  } else {
    attn_fallback<<<dim3(NT / 2 * NHEADS), dim3(256), 0, stream>>>(Q, K, V, out);
  }
}

// Round 9
// 145.372 us; speedup vs baseline: 1.1625x; 1.1625x over previous
//
#include <hip/hip_runtime.h>
#include <hip/hip_bf16.h>

// B=2 H=16 S=2048 D=64, causal. Output = context (B,H,S,D) ++ attention (B,H,S,S), fp32.
// prep: fp32->bf16 pre-swizzled tile images in d_ws. main: R7 structure (uniform-work
// pair blocks, XCD-pinned heads, gl_lds dbuf staging) + counted-vmcnt phase-2 barriers
// (att stores stay in flight across barriers) + Q fragments direct from image.

constexpr int SEQ = 2048;
constexpr int HD  = 64;
constexpr int NHEADS = 32;   // B*H
constexpr int QT  = 64;
constexpr int NT  = SEQ / QT;

typedef __bf16 bf16x8 __attribute__((ext_vector_type(8)));
typedef unsigned short u16x8 __attribute__((ext_vector_type(8)));
typedef unsigned short u16x4 __attribute__((ext_vector_type(4)));
typedef float f32x4 __attribute__((ext_vector_type(4)));
typedef unsigned short us;

__device__ __forceinline__ us f2bf(float x) {
  unsigned u = __builtin_bit_cast(unsigned, x);
  return (us)((u + 0x7fffu + ((u >> 16) & 1u)) >> 16);  // RNE
}
__device__ __forceinline__ float bf2f(us b) {
  return __builtin_bit_cast(float, (unsigned)b << 16);
}

#define GLOAD_LDS(gp, lp)                                                        \
  __builtin_amdgcn_global_load_lds(                                             \
      (const __attribute__((address_space(1))) void*)(gp),                      \
      (__attribute__((address_space(3))) void*)(lp), 16, 0, 0)

// stage one 8KB tile image -> LDS: 4 waves x 2 calls x 64 lanes x 16B
__device__ __forceinline__ void stage8k(const us* img, us* lds, int w, int l) {
  const char* g = (const char*)img + w * 2048 + l * 16;
  char* s = (char*)lds + w * 2048;
  GLOAD_LDS(g, s);
  GLOAD_LDS(g + 1024, s + 1024);
}

// ============ prep: build bf16 pre-swizzled tile images in scratch ============
// image elem (row r, col c) of Q/K tile at u16-idx (r*64+c) ^ ((r&7)<<3)
// image elem V^T (d, key)            at u16-idx (d*64+key) ^ ((d&7)<<3)
__global__ void prep_kernel(const float* __restrict__ Qg,
                            const float* __restrict__ Kg,
                            const float* __restrict__ Vg,
                            us* __restrict__ ws) {
  const int tile = blockIdx.x & (NT - 1);
  const int bh   = blockIdx.x >> 5;
  const int t = threadIdx.x;
  const size_t tOff = ((size_t)bh * SEQ + (size_t)tile * QT) * HD;
  us* Qi = ws + ((size_t)bh * NT + tile) * 4096;
  us* Ki = Qi + (size_t)NHEADS * NT * 4096;
  us* Vi = Ki + (size_t)NHEADS * NT * 4096;

  #pragma unroll
  for (int g0 = 0; g0 < 2; ++g0) {
    const int g = t + 256 * g0;          // 0..511 image chunks of 8 u16
    const int r = g >> 3, c8 = g & 7;
    const int cp = (8 * c8) ^ ((r & 7) << 3);   // source col for this chunk
    const float* qs = Qg + tOff + (size_t)r * HD + cp;
    const float* ks = Kg + tOff + (size_t)r * HD + cp;
    u16x8 q, k;
    #pragma unroll
    for (int j = 0; j < 8; ++j) { q[j] = f2bf(qs[j]); k[j] = f2bf(ks[j]); }
    *(u16x8*)(Qi + 8 * g) = q;
    *(u16x8*)(Ki + 8 * g) = k;
  }
  #pragma unroll
  for (int g0 = 0; g0 < 2; ++g0) {
    const int g = t + 256 * g0;
    const int d = g >> 3, k8 = g & 7;
    const int kp = (8 * k8) ^ ((d & 7) << 3);   // source key for this chunk
    const float* vs = Vg + tOff + d;
    u16x8 v;
    #pragma unroll
    for (int j = 0; j < 8; ++j) v[j] = f2bf(vs[(size_t)(kp + j) * HD]);
    *(u16x8*)(Vi + 8 * g) = v;
  }
}

// ======================= main attention kernel =======================
__launch_bounds__(256, 3)
__global__ void attn_main(const us* __restrict__ ws, float* __restrict__ out) {
  const int fb = blockIdx.x;           // 0..511
  const int bh = fb & (NHEADS - 1);    // fb%8 == bh%8 -> head pinned to one XCD
  const int pi = fb >> 5;              // 0..15 pair index: q-tiles pi and 31-pi
  const int t  = threadIdx.x;
  const int l  = t & 63;
  const int w  = t >> 6;
  const int l16 = l & 15;
  const int lg  = l >> 4;

  __shared__ __align__(16) us Ks[2][4096];
  __shared__ __align__(16) us Vs[2][4096];     // V^T images
  __shared__ __align__(16) us Ps[4][1024];     // per-wave P strip [q=16][k=64]

  const us* Qi = ws + (size_t)bh * NT * 4096;
  const us* Ki = Qi + (size_t)NHEADS * NT * 4096;
  const us* Vi = Ki + (size_t)NHEADS * NT * 4096;

  float* ctx = out + (size_t)bh * SEQ * HD;
  float* att = out + (size_t)NHEADS * SEQ * HD + (size_t)bh * SEQ * SEQ;

  const float KC = 0.18033688011112042f;  // (1/8) * log2(e)

  for (int half = 0; half < 2; ++half) {
    const int qt = half ? (NT - 1 - pi) : pi;
    const int qbase = qt * QT;
    const int qg = qbase + w * 16 + l16;     // lane's q-row (S^T: col=l16)

    // issue first K stage; Q fragments direct from image; zero-fill overlaps
    stage8k(Ki, Ks[0], w, l);
    bf16x8 aq[2];
    {
      const int qr = w * 16 + l16;
      #pragma unroll
      for (int ks = 0; ks < 2; ++ks) {
        const int idx = (qr * 64 + ks * 32 + lg * 8) ^ ((qr & 7) << 3);
        aq[ks] = __builtin_bit_cast(bf16x8, *(const u16x8*)(&Qi[(size_t)qt * 4096 + idx]));
      }
    }
    {
      const int zc0 = (qt + 1) * QT;
      const int nz4 = (SEQ - zc0) >> 2;
      for (int rr = 0; rr < QT; ++rr) {
        float* rowp = att + (size_t)(qbase + rr) * SEQ + zc0;
        for (int c = t; c < nz4; c += 256)
          __builtin_nontemporal_store((f32x4){0.f, 0.f, 0.f, 0.f}, (f32x4*)(rowp + 4 * c));
      }
    }
    __syncthreads();   // full drain: staging + zero-fill

    // ================= phase 1: row sums =================
    float rsum = 0.f;
    {
      int cur = 0;
      for (int kt = 0; kt <= qt; ++kt) {
        if (kt < qt) stage8k(Ki + (size_t)(kt + 1) * 4096, Ks[cur ^ 1], w, l);
        const us* krb = Ks[cur];
        const int kb = kt * QT;
        #pragma unroll
        for (int ct = 0; ct < 4; ++ct) {
          f32x4 acc = {0.f, 0.f, 0.f, 0.f};
          #pragma unroll
          for (int ks = 0; ks < 2; ++ks) {
            const int kr = ct * 16 + l16;
            const int idx = (kr * 64 + ks * 32 + lg * 8) ^ ((kr & 7) << 3);
            bf16x8 bk = __builtin_bit_cast(bf16x8, *(const u16x8*)(&krb[idx]));
            acc = __builtin_amdgcn_mfma_f32_16x16x32_bf16(bk, aq[ks], acc, 0, 0, 0);
          }
          const int kg0 = kb + ct * 16 + lg * 4;
          #pragma unroll
          for (int rr = 0; rr < 4; ++rr) {
            float e = __builtin_amdgcn_exp2f(acc[rr] * KC);
            rsum += (kg0 + rr <= qg) ? e : 0.f;
          }
        }
        __syncthreads();   // drains the 2 staging loads (needed anyway; no stores here)
        cur ^= 1;
      }
    }
    // stage phase-2 tile 0 while reducing
    stage8k(Ki, Ks[0], w, l);
    stage8k(Vi, Vs[0], w, l);
    rsum += __shfl_xor(rsum, 16);
    rsum += __shfl_xor(rsum, 32);
    const float inv = 1.f / rsum;
    __syncthreads();   // full drain before phase 2

    // ================= phase 2: P -> att + O = P·V =================
    f32x4 oacc[4];
    #pragma unroll
    for (int ct = 0; ct < 4; ++ct) oacc[ct] = (f32x4){0.f, 0.f, 0.f, 0.f};

    {
      int cur = 0;
      for (int kt = 0; kt <= qt; ++kt) {
        if (kt < qt) {
          stage8k(Ki + (size_t)(kt + 1) * 4096, Ks[cur ^ 1], w, l);
          stage8k(Vi + (size_t)(kt + 1) * 4096, Vs[cur ^ 1], w, l);
        }
        __builtin_amdgcn_sched_barrier(0);   // pin 4 gl_lds before compute+stores
        const us* krb = Ks[cur];
        const us* vrb = Vs[cur];
        const int kb = kt * QT;

        // QK^T (swapped) -> normalized bf16 P into own-wave Ps
        #pragma unroll
        for (int ct = 0; ct < 4; ++ct) {
          f32x4 acc = {0.f, 0.f, 0.f, 0.f};
          #pragma unroll
          for (int ks = 0; ks < 2; ++ks) {
            const int kr = ct * 16 + l16;
            const int idx = (kr * 64 + ks * 32 + lg * 8) ^ ((kr & 7) << 3);
            bf16x8 bk = __builtin_bit_cast(bf16x8, *(const u16x8*)(&krb[idx]));
            acc = __builtin_amdgcn_mfma_f32_16x16x32_bf16(bk, aq[ks], acc, 0, 0, 0);
          }
          const int kg0 = kb + ct * 16 + lg * 4;
          u16x4 pb;
          #pragma unroll
          for (int rr = 0; rr < 4; ++rr) {
            float e = __builtin_amdgcn_exp2f(acc[rr] * KC) * inv;
            pb[rr] = f2bf((kg0 + rr <= qg) ? e : 0.f);
          }
          const int pidx = (l16 * 64 + ct * 16 + lg * 4) ^ ((l16 & 7) << 3);
          *(u16x4*)(&Ps[w][pidx]) = pb;
        }

        // att copy: own-wave rows, 256B/row contiguous, nontemporal (4 stores)
        #pragma unroll
        for (int j = 0; j < 4; ++j) {
          const int rloc = lg + 4 * j;
          const int idx = (rloc * 64 + 4 * l16) ^ ((rloc & 7) << 3);
          u16x4 p4 = *(const u16x4*)(&Ps[w][idx]);
          f32x4 pv = { bf2f(p4[0]), bf2f(p4[1]), bf2f(p4[2]), bf2f(p4[3]) };
          __builtin_nontemporal_store(pv,
              (f32x4*)(att + (size_t)(qbase + w * 16 + rloc) * SEQ + kb + 4 * l16));
        }

        // PV (swapped): A = V^T via b128, B = P^T strip (own-wave)
        bf16x8 pa[2];
        #pragma unroll
        for (int ks = 0; ks < 2; ++ks) {
          const int pidx = (l16 * 64 + ks * 32 + lg * 8) ^ ((l16 & 7) << 3);
          pa[ks] = __builtin_bit_cast(bf16x8, *(const u16x8*)(&Ps[w][pidx]));
        }
        #pragma unroll
        for (int ct = 0; ct < 4; ++ct) {
          #pragma unroll
          for (int ks = 0; ks < 2; ++ks) {
            const int dr = ct * 16 + l16;
            const int vidx = (dr * 64 + ks * 32 + lg * 8) ^ ((dr & 7) << 3);
            bf16x8 av = __builtin_bit_cast(bf16x8, *(const u16x8*)(&vrb[vidx]));
            oacc[ct] = __builtin_amdgcn_mfma_f32_16x16x32_bf16(av, pa[ks], oacc[ct], 0, 0, 0);
          }
        }

        // counted barrier: [4 gl_lds][4 att stores] in order -> vmcnt(4) retires
        // prev-iter stores + this iter's staging; 4 newest att stores stay in flight
        if (kt < qt) {
          asm volatile("s_waitcnt vmcnt(4) lgkmcnt(0)" ::: "memory");
        } else {
          asm volatile("s_waitcnt lgkmcnt(0)" ::: "memory");
        }
        __builtin_amdgcn_s_barrier();
        __builtin_amdgcn_sched_barrier(0);
        cur ^= 1;
      }
    }

    // ---- context write: lane q=l16 row, d = ct*16+lg*4+rr ----
    #pragma unroll
    for (int ct = 0; ct < 4; ++ct)
      __builtin_nontemporal_store(oacc[ct],
          (f32x4*)(ctx + (size_t)qg * HD + ct * 16 + lg * 4));
  }
}

// ======================= fallback (R6, proven 153us) =======================
__launch_bounds__(256, 2)
__global__ void attn_fallback(const float* __restrict__ Qg,
                              const float* __restrict__ Kg,
                              const float* __restrict__ Vg,
                              float* __restrict__ out) {
  const int fb = blockIdx.x;
  const int bh = fb & (NHEADS - 1);
  const int pi = fb >> 5;
  const int t  = threadIdx.x;
  const int l  = t & 63;
  const int w  = t >> 6;
  const int l16 = l & 15;
  const int lg  = l >> 4;

  __shared__ __align__(16) us Qs[QT * HD];
  __shared__ __align__(16) us Ks[QT * HD];
  __shared__ __align__(16) us Vs[QT * HD];
  __shared__ __align__(16) us Ps[4][16 * QT];

  const size_t hoff = (size_t)bh * SEQ * HD;
  const float* Qh = Qg + hoff;
  const float* Kh = Kg + hoff;
  const float* Vh = Vg + hoff;
  float* ctx = out + hoff;
  float* att = out + (size_t)NHEADS * SEQ * HD + (size_t)bh * SEQ * SEQ;

  auto load_tile = [&](const float* src, f32x4 (&reg)[4]) {
    #pragma unroll
    for (int j = 0; j < 4; ++j) {
      const int f = t + 256 * j;
      reg[j] = *(const f32x4*)(src + (size_t)(f >> 4) * HD + 4 * (f & 15));
    }
  };
  auto write_k = [&](const f32x4 (&reg)[4], us* dst) {
    #pragma unroll
    for (int j = 0; j < 4; ++j) {
      const int f = t + 256 * j;
      const int rr = f >> 4, c4 = f & 15;
      const int idx = (rr * 64 + 4 * c4) ^ ((rr & 7) << 3);
      u16x4 b = { f2bf(reg[j].x), f2bf(reg[j].y), f2bf(reg[j].z), f2bf(reg[j].w) };
      *(u16x4*)(&dst[idx]) = b;
    }
  };
  auto write_vv = [&](const f32x4 (&reg)[4], us* dst) {
    #pragma unroll
    for (int j = 0; j < 4; ++j) {
      const int f = t + 256 * j;
      const int rr = f >> 4, c4 = f & 15;
      const int idx = (rr * 64 + 4 * c4) ^ (((rr >> 3) & 3) << 4);
      u16x4 b = { f2bf(reg[j].x), f2bf(reg[j].y), f2bf(reg[j].z), f2bf(reg[j].w) };
      *(u16x4*)(&dst[idx]) = b;
    }
  };

  const float sc = 0.125f;

  for (int half = 0; half < 2; ++half) {
    const int qt = half ? (NT - 1 - pi) : pi;
    const int qbase = qt * QT;
    const int qg = qbase + w * 16 + l16;

    __syncthreads();
    {
      const int zc0 = (qt + 1) * QT;
      const int nz4 = (SEQ - zc0) >> 2;
      for (int rr = 0; rr < QT; ++rr) {
        float* rowp = att + (size_t)(qbase + rr) * SEQ + zc0;
        for (int c = t; c < nz4; c += 256)
          __builtin_nontemporal_store((f32x4){0.f, 0.f, 0.f, 0.f}, (f32x4*)(rowp + 4 * c));
      }
    }
    {
      f32x4 qreg[4];
      load_tile(Qh + (size_t)qbase * HD, qreg);
      write_k(qreg, Qs);
    }
    __syncthreads();

    bf16x8 aq[2];
    #pragma unroll
    for (int ks = 0; ks < 2; ++ks) {
      const int qr = w * 16 + l16;
      const int idx = (qr * 64 + ks * 32 + lg * 8) ^ ((qr & 7) << 3);
      aq[ks] = __builtin_bit_cast(bf16x8, *(const u16x8*)(&Qs[idx]));
    }

    float rsum = 0.f;
    {
      f32x4 kreg[4];
      load_tile(Kh, kreg);
      write_k(kreg, Ks);
      __syncthreads();
      for (int kt = 0; kt <= qt; ++kt) {
        if (kt < qt) load_tile(Kh + (size_t)(kt + 1) * QT * HD, kreg);
        const int kb = kt * QT;
        #pragma unroll
        for (int ct = 0; ct < 4; ++ct) {
          f32x4 acc = {0.f, 0.f, 0.f, 0.f};
          #pragma unroll
          for (int ks = 0; ks < 2; ++ks) {
            const int kr = ct * 16 + l16;
            const int idx = (kr * 64 + ks * 32 + lg * 8) ^ ((kr & 7) << 3);
            bf16x8 bk = __builtin_bit_cast(bf16x8, *(const u16x8*)(&Ks[idx]));
            acc = __builtin_amdgcn_mfma_f32_16x16x32_bf16(bk, aq[ks], acc, 0, 0, 0);
          }
          const int kg0 = kb + ct * 16 + lg * 4;
          #pragma unroll
          for (int rr = 0; rr < 4; ++rr) {
            float e = __expf(acc[rr] * sc);
            rsum += (kg0 + rr <= qg) ? e : 0.f;
          }
        }
        __syncthreads();
        if (kt < qt) write_k(kreg, Ks);
        __syncthreads();
      }
    }
    rsum += __shfl_xor(rsum, 16);
    rsum += __shfl_xor(rsum, 32);
    const float inv = 1.f / rsum;

    f32x4 oacc[4];
    #pragma unroll
    for (int ct = 0; ct < 4; ++ct) oacc[ct] = (f32x4){0.f, 0.f, 0.f, 0.f};

    {
      f32x4 kreg[4], vreg[4];
      load_tile(Kh, kreg);
      load_tile(Vh, vreg);
      write_k(kreg, Ks);
      write_vv(vreg, Vs);
      __syncthreads();
      for (int kt = 0; kt <= qt; ++kt) {
        if (kt < qt) {
          load_tile(Kh + (size_t)(kt + 1) * QT * HD, kreg);
          load_tile(Vh + (size_t)(kt + 1) * QT * HD, vreg);
        }
        const int kb = kt * QT;
        #pragma unroll
        for (int ct = 0; ct < 4; ++ct) {
          f32x4 acc = {0.f, 0.f, 0.f, 0.f};
          #pragma unroll
          for (int ks = 0; ks < 2; ++ks) {
            const int kr = ct * 16 + l16;
            const int idx = (kr * 64 + ks * 32 + lg * 8) ^ ((kr & 7) << 3);
            bf16x8 bk = __builtin_bit_cast(bf16x8, *(const u16x8*)(&Ks[idx]));
            acc = __builtin_amdgcn_mfma_f32_16x16x32_bf16(bk, aq[ks], acc, 0, 0, 0);
          }
          const int kg0 = kb + ct * 16 + lg * 4;
          u16x4 pb;
          #pragma unroll
          for (int rr = 0; rr < 4; ++rr) {
            float e = __expf(acc[rr] * sc) * inv;
            pb[rr] = f2bf((kg0 + rr <= qg) ? e : 0.f);
          }
          const int pidx = (l16 * 64 + ct * 16 + lg * 4) ^ ((l16 & 7) << 3);
          *(u16x4*)(&Ps[w][pidx]) = pb;
        }
        #pragma unroll
        for (int ct = 0; ct < 4; ++ct) {
          #pragma unroll
          for (int ks = 0; ks < 2; ++ks) {
            const int key0 = ks * 32 + lg * 8;
            const int pidx = (l16 * 64 + key0) ^ ((l16 & 7) << 3);
            bf16x8 pa = __builtin_bit_cast(bf16x8, *(const u16x8*)(&Ps[w][pidx]));
            bf16x8 av;
            const int dcol = ct * 16 + l16;
            const int xorv = ((key0 >> 3) & 3) << 4;
            #pragma unroll
            for (int j = 0; j < 8; ++j)
              av[j] = __builtin_bit_cast(__bf16, Vs[((key0 + j) * 64 + dcol) ^ xorv]);
            oacc[ct] = __builtin_amdgcn_mfma_f32_16x16x32_bf16(av, pa, oacc[ct], 0, 0, 0);
          }
        }
        __syncthreads();
        #pragma unroll
        for (int j = 0; j < 4; ++j) {
          const int f = t + 256 * j;
          const int rr = f >> 4, c4 = f & 15;
          const int ww = rr >> 4, qr = rr & 15;
          const int idx = (qr * 64 + 4 * c4) ^ ((qr & 7) << 3);
          u16x4 pb = *(const u16x4*)(&Ps[ww][idx]);
          f32x4 pv = { bf2f(pb[0]), bf2f(pb[1]), bf2f(pb[2]), bf2f(pb[3]) };
          __builtin_nontemporal_store(pv,
              (f32x4*)(att + (size_t)(qbase + rr) * SEQ + kb + 4 * c4));
        }
        if (kt < qt) {
          write_k(kreg, Ks);
          write_vv(vreg, Vs);
        }
        __syncthreads();
      }
    }
    #pragma unroll
    for (int ct = 0; ct < 4; ++ct)
      *(f32x4*)(ctx + (size_t)qg * HD + ct * 16 + lg * 4) = oacc[ct];
  }
}

extern "C" void kernel_launch(void* const* d_in, const int* in_sizes, int n_in,
                              void* d_out, int out_size, void* d_ws, size_t ws_size,
                              hipStream_t stream) {
  const float* Q = (const float*)d_in[0];
  const float* K = (const float*)d_in[1];
  const float* V = (const float*)d_in[2];
  float* out = (float*)d_out;
  const size_t NEED = (size_t)3 * NHEADS * NT * 4096 * sizeof(us);  // 25.2 MB
  if (ws_size >= NEED && d_ws != nullptr) {
    us* wsp = (us*)d_ws;
    prep_kernel<<<dim3(NHEADS * NT), dim3(256), 0, stream>>>(Q, K, V, wsp);
    attn_main<<<dim3(NT / 2 * NHEADS), dim3(256), 0, stream>>>(wsp, out);
  } else {
    attn_fallback<<<dim3(NT / 2 * NHEADS), dim3(256), 0, stream>>>(Q, K, V, out);
  }
}